// Round 1
// baseline (28050.070 us; speedup 1.0000x reference)
//
#include <hip/hip_runtime.h>

typedef unsigned int uint;

#define SEQ 4096
#define EMB 300
#define HID 500
#define NG 2000      // 4*HID
#define KX 600       // 2*EMB
#define KXP 608      // padded K for aligned float4 loads

#define BM 64
#define BN 64
#define BK 16

#define NWG 50       // workgroups in recurrence
#define UPW 10       // hidden units per workgroup
#define RWS 40       // 4*UPW gate rows per workgroup
#define TPB 320      // 8 lanes per row * 40 rows

// ---------------------------------------------------------------- gather x
__global__ __launch_bounds__(256) void gather_x(const int* __restrict__ words,
                                                const int* __restrict__ labels,
                                                const float* __restrict__ embw,
                                                const float* __restrict__ embe,
                                                float* __restrict__ x) {
  int t = blockIdx.x;
  int w = words[t], l = labels[t];
  const float* rw = embw + (size_t)w * EMB;
  const float* re = embe + (size_t)l * EMB;
  float* xr = x + (size_t)t * KXP;
  for (int k = threadIdx.x; k < KXP; k += 256) {
    float v = 0.f;
    if (k < EMB) v = rw[k];
    else if (k < KX) v = re[k - EMB];
    xr[k] = v;  // pads [600,608) zeroed
  }
}

// ---------------------------------------------------------------- pre GEMM
// pre[t][n] = sum_k x[t][k] * Wih[n][k] + bih[n] + bhh[n]
__global__ __launch_bounds__(256) void gemm_pre(const float* __restrict__ x,
                                                const float* __restrict__ Wih,
                                                const float* __restrict__ bih,
                                                const float* __restrict__ bhh,
                                                float* __restrict__ pre) {
  __shared__ float As[BK][BM + 4];
  __shared__ float Bs[BK][BN + 4];
  const int m0 = blockIdx.x * BM;
  const int n0 = blockIdx.y * BN;
  const int tid = threadIdx.x;
  const int tx = tid & 15, ty = tid >> 4;
  const int lrow = tid >> 2;          // 0..63
  const int lc4 = (tid & 3) << 2;     // 0,4,8,12
  float acc[4][4] = {};

  for (int kk = 0; kk < KX; kk += BK) {
    float4 av = *(const float4*)(x + (size_t)(m0 + lrow) * KXP + kk + lc4);
    int brow = n0 + lrow; if (brow >= NG) brow = 0;
    float4 bv;
    if (kk + lc4 + 3 < KX) {
      bv = *(const float4*)(Wih + (size_t)brow * KX + kk + lc4);
    } else {
      float tmp[4];
#pragma unroll
      for (int j = 0; j < 4; ++j) {
        int k = kk + lc4 + j;
        tmp[j] = (k < KX) ? Wih[(size_t)brow * KX + k] : 0.f;
      }
      bv = make_float4(tmp[0], tmp[1], tmp[2], tmp[3]);
    }
    As[lc4 + 0][lrow] = av.x; As[lc4 + 1][lrow] = av.y;
    As[lc4 + 2][lrow] = av.z; As[lc4 + 3][lrow] = av.w;
    Bs[lc4 + 0][lrow] = bv.x; Bs[lc4 + 1][lrow] = bv.y;
    Bs[lc4 + 2][lrow] = bv.z; Bs[lc4 + 3][lrow] = bv.w;
    __syncthreads();
#pragma unroll
    for (int k = 0; k < BK; ++k) {
      float4 a = *(const float4*)&As[k][ty << 2];
      float4 b = *(const float4*)&Bs[k][tx << 2];
      acc[0][0] += a.x * b.x; acc[0][1] += a.x * b.y; acc[0][2] += a.x * b.z; acc[0][3] += a.x * b.w;
      acc[1][0] += a.y * b.x; acc[1][1] += a.y * b.y; acc[1][2] += a.y * b.z; acc[1][3] += a.y * b.w;
      acc[2][0] += a.z * b.x; acc[2][1] += a.z * b.y; acc[2][2] += a.z * b.z; acc[2][3] += a.z * b.w;
      acc[3][0] += a.w * b.x; acc[3][1] += a.w * b.y; acc[3][2] += a.w * b.z; acc[3][3] += a.w * b.w;
    }
    __syncthreads();
  }
#pragma unroll
  for (int i = 0; i < 4; ++i) {
    int m = m0 + (ty << 2) + i;
#pragma unroll
    for (int j = 0; j < 4; ++j) {
      int n = n0 + (tx << 2) + j;
      if (n < NG) pre[(size_t)m * NG + n] = acc[i][j] + bih[n] + bhh[n];
    }
  }
}

// ---------------------------------------------------------------- sync init
__global__ void init_sync(float* hbuf, int* flags) {
  int i = threadIdx.x;
  if (i < 1024) hbuf[i] = 0.f;   // both h double-buffers (h_0 = 0)
  if (i < 64) flags[i] = 0;
}

// ---------------------------------------------------------------- recurrence
__device__ __forceinline__ uint f2bf(float f) {
  uint u = __float_as_uint(f);
  return (u + 0x7fffu + ((u >> 16) & 1u)) >> 16;  // RNE to bf16
}
__device__ __forceinline__ float sigm(float x) { return 1.f / (1.f + __expf(-x)); }

__global__ __launch_bounds__(TPB) void lstm_seq(const float* __restrict__ pre,
                                                const float* __restrict__ Whh,
                                                const float* __restrict__ fcw,
                                                const float* __restrict__ fcb,
                                                float* hbuf, int* flags,
                                                float* __restrict__ out) {
  __shared__ uint Wl[RWS][256];      // bf16-pair packed, cols padded to 512
  __shared__ float h_lds[512];
  __shared__ float gates[RWS];
  __shared__ float c_lds[UPW];

  const int g = blockIdx.x;
  const int tid = threadIdx.x;
  const int r = tid >> 3;            // local gate-row 0..39
  const int cc = tid & 7;            // col-chunk 0..7 (64 cols each)
  const int my_prerow = (r / UPW) * HID + g * UPW + (r % UPW);

  // stage W_hh slice: local row r = gate*UPW + ul -> global row gate*HID + g*UPW + ul
  for (int i = tid; i < RWS * 256; i += TPB) {
    int rr = i >> 8, cp = i & 255;
    int gi = rr / UPW, ul = rr % UPW;
    size_t grow = (size_t)(gi * HID + g * UPW + ul) * HID;
    int c0 = cp * 2, c1 = c0 + 1;
    float v0 = (c0 < HID) ? Whh[grow + c0] : 0.f;
    float v1 = (c1 < HID) ? Whh[grow + c1] : 0.f;
    Wl[rr][cp] = f2bf(v0) | (f2bf(v1) << 16);
  }
  if (tid < UPW) c_lds[tid] = 0.f;
  if (tid < 12) h_lds[500 + tid] = 0.f;  // pads, written once

  const uint* wrow = &Wl[r][cc * 32];
  const float* hrow = &h_lds[cc * 64];

  for (int t = 0; t < SEQ; ++t) {
    // wave 0 polls all 50 per-WG flags (distinct addresses -> no contention)
    if (tid < 64) {
      while (true) {
        int f = t;
        if (tid < NWG) f = __hip_atomic_load(&flags[tid], __ATOMIC_RELAXED, __HIP_MEMORY_SCOPE_AGENT);
        if (__all(f >= t)) break;
        __builtin_amdgcn_s_sleep(1);
      }
    }
    __syncthreads();
    __builtin_amdgcn_fence(__ATOMIC_ACQUIRE, "agent");

    // prefetch this WG's pre[t] slice (consumed after the reduce)
    float pre_v = 0.f;
    if (cc == 0) pre_v = pre[(size_t)t * NG + my_prerow];

    // stage h_t from LLC-coherent double buffer
    float* hb = hbuf + (t & 1) * 512;
    float a0 = __hip_atomic_load(&hb[tid], __ATOMIC_RELAXED, __HIP_MEMORY_SCOPE_AGENT);
    float a1 = 0.f;
    if (tid < HID - TPB) a1 = __hip_atomic_load(&hb[tid + TPB], __ATOMIC_RELAXED, __HIP_MEMORY_SCOPE_AGENT);
    h_lds[tid] = a0;
    if (tid < HID - TPB) h_lds[tid + TPB] = a1;
    __syncthreads();

    // 8 lanes per row, 64 contiguous cols each: b128 LDS reads, bf16 unpack, fp32 FMA
    float acc = 0.f;
#pragma unroll
    for (int q = 0; q < 8; ++q) {
      uint4 u = *(const uint4*)(wrow + q * 4);
      float4 h0 = *(const float4*)(hrow + q * 8);
      float4 h1 = *(const float4*)(hrow + q * 8 + 4);
      acc += __uint_as_float(u.x << 16) * h0.x;
      acc += __uint_as_float(u.x & 0xffff0000u) * h0.y;
      acc += __uint_as_float(u.y << 16) * h0.z;
      acc += __uint_as_float(u.y & 0xffff0000u) * h0.w;
      acc += __uint_as_float(u.z << 16) * h1.x;
      acc += __uint_as_float(u.z & 0xffff0000u) * h1.y;
      acc += __uint_as_float(u.w << 16) * h1.z;
      acc += __uint_as_float(u.w & 0xffff0000u) * h1.w;
    }
    acc += __shfl_xor(acc, 1);
    acc += __shfl_xor(acc, 2);
    acc += __shfl_xor(acc, 4);
    if (cc == 0) gates[r] = acc + pre_v;
    __syncthreads();

    if (tid < UPW) {
      float iv = sigm(gates[tid]);
      float fv = sigm(gates[UPW + tid]);
      float gv = tanhf(gates[2 * UPW + tid]);
      float ov = sigm(gates[3 * UPW + tid]);
      float c = fv * c_lds[tid] + iv * gv;
      c_lds[tid] = c;
      float h = ov * tanhf(c);
      __hip_atomic_store(&hbuf[((t + 1) & 1) * 512 + g * UPW + tid], h,
                         __ATOMIC_RELAXED, __HIP_MEMORY_SCOPE_AGENT);
    }
    __syncthreads();  // drains the h stores (vmcnt) before the flag release
    if (tid == 0)
      __hip_atomic_store(&flags[g], t + 1, __ATOMIC_RELEASE, __HIP_MEMORY_SCOPE_AGENT);
  }

  // final FC by WG 0: out = fc_w @ h_4096 + fc_b
  if (g == 0) {
    if (tid < 64) {
      while (true) {
        int f = SEQ;
        if (tid < NWG) f = __hip_atomic_load(&flags[tid], __ATOMIC_RELAXED, __HIP_MEMORY_SCOPE_AGENT);
        if (__all(f >= SEQ)) break;
        __builtin_amdgcn_s_sleep(1);
      }
    }
    __syncthreads();
    __builtin_amdgcn_fence(__ATOMIC_ACQUIRE, "agent");
    h_lds[tid] = __hip_atomic_load(&hbuf[tid], __ATOMIC_RELAXED, __HIP_MEMORY_SCOPE_AGENT);
    if (tid < HID - TPB)
      h_lds[tid + TPB] = __hip_atomic_load(&hbuf[tid + TPB], __ATOMIC_RELAXED, __HIP_MEMORY_SCOPE_AGENT);
    __syncthreads();
    int row = tid >> 4, ln = tid & 15;   // 20 rows x 16 lanes = 320
    float s = 0.f;
    for (int j = ln; j < HID; j += 16) s += fcw[row * HID + j] * h_lds[j];
    s += __shfl_xor(s, 1); s += __shfl_xor(s, 2);
    s += __shfl_xor(s, 4); s += __shfl_xor(s, 8);
    if (ln == 0) out[row] = s + fcb[row];
  }
}

// ---------------------------------------------------------------- launch
extern "C" void kernel_launch(void* const* d_in, const int* in_sizes, int n_in,
                              void* d_out, int out_size, void* d_ws, size_t ws_size,
                              hipStream_t stream) {
  const int* words = (const int*)d_in[0];
  const int* labels = (const int*)d_in[1];
  const float* embw = (const float*)d_in[2];
  const float* embe = (const float*)d_in[3];
  const float* Wih = (const float*)d_in[4];
  const float* Whh = (const float*)d_in[5];
  const float* bih = (const float*)d_in[6];
  const float* bhh = (const float*)d_in[7];
  const float* fcw = (const float*)d_in[8];
  const float* fcb = (const float*)d_in[9];
  float* out = (float*)d_out;

  char* ws = (char*)d_ws;
  float* x = (float*)ws;                                             // 4096*608*4  = 9.96 MB
  float* pre = (float*)(ws + (size_t)SEQ * KXP * 4);                 // 4096*2000*4 = 32.77 MB
  float* hbuf = (float*)(ws + (size_t)SEQ * KXP * 4 + (size_t)SEQ * NG * 4);  // 2*512*4
  int* flags = (int*)((char*)hbuf + 2 * 512 * 4);                    // 64*4

  gather_x<<<SEQ, 256, 0, stream>>>(words, labels, embw, embe, x);
  dim3 ggrid(SEQ / BM, (NG + BN - 1) / BN);
  gemm_pre<<<ggrid, 256, 0, stream>>>(x, Wih, bih, bhh, pre);
  init_sync<<<1, 1024, 0, stream>>>(hbuf, flags);
  lstm_seq<<<NWG, TPB, 0, stream>>>(pre, Whh, fcw, fcb, hbuf, flags, out);
}

// Round 2
// 11889.928 us; speedup vs baseline: 2.3591x; 2.3591x over previous
//
#include <hip/hip_runtime.h>

typedef unsigned int uint;
typedef unsigned long long u64;

#define SEQ 4096
#define EMB 300
#define HID 500
#define NG 2000      // 4*HID
#define KX 600       // 2*EMB
#define KXP 608      // padded K for aligned float4 loads

#define BM 64
#define BN 64
#define BK 16

#define NWG 50       // workgroups in recurrence
#define UPW 10       // hidden units per workgroup
#define RWS 40       // 4*UPW gate rows per workgroup
#define TPB 320      // 8 lanes per row * 40 rows
#define HSLOT 512    // padded h slots per double-buffer half

// ---------------------------------------------------------------- gather x
__global__ __launch_bounds__(256) void gather_x(const int* __restrict__ words,
                                                const int* __restrict__ labels,
                                                const float* __restrict__ embw,
                                                const float* __restrict__ embe,
                                                float* __restrict__ x) {
  int t = blockIdx.x;
  int w = words[t], l = labels[t];
  const float* rw = embw + (size_t)w * EMB;
  const float* re = embe + (size_t)l * EMB;
  float* xr = x + (size_t)t * KXP;
  for (int k = threadIdx.x; k < KXP; k += 256) {
    float v = 0.f;
    if (k < EMB) v = rw[k];
    else if (k < KX) v = re[k - EMB];
    xr[k] = v;  // pads [600,608) zeroed
  }
}

// ---------------------------------------------------------------- pre GEMM
// pre[t][n] = sum_k x[t][k] * Wih[n][k] + bih[n] + bhh[n]
__global__ __launch_bounds__(256) void gemm_pre(const float* __restrict__ x,
                                                const float* __restrict__ Wih,
                                                const float* __restrict__ bih,
                                                const float* __restrict__ bhh,
                                                float* __restrict__ pre) {
  __shared__ float As[BK][BM + 4];
  __shared__ float Bs[BK][BN + 4];
  const int m0 = blockIdx.x * BM;
  const int n0 = blockIdx.y * BN;
  const int tid = threadIdx.x;
  const int tx = tid & 15, ty = tid >> 4;
  const int lrow = tid >> 2;          // 0..63
  const int lc4 = (tid & 3) << 2;     // 0,4,8,12
  float acc[4][4] = {};

  for (int kk = 0; kk < KX; kk += BK) {
    float4 av = *(const float4*)(x + (size_t)(m0 + lrow) * KXP + kk + lc4);
    int brow = n0 + lrow; if (brow >= NG) brow = 0;
    float4 bv;
    if (kk + lc4 + 3 < KX) {
      bv = *(const float4*)(Wih + (size_t)brow * KX + kk + lc4);
    } else {
      float tmp[4];
#pragma unroll
      for (int j = 0; j < 4; ++j) {
        int k = kk + lc4 + j;
        tmp[j] = (k < KX) ? Wih[(size_t)brow * KX + k] : 0.f;
      }
      bv = make_float4(tmp[0], tmp[1], tmp[2], tmp[3]);
    }
    As[lc4 + 0][lrow] = av.x; As[lc4 + 1][lrow] = av.y;
    As[lc4 + 2][lrow] = av.z; As[lc4 + 3][lrow] = av.w;
    Bs[lc4 + 0][lrow] = bv.x; Bs[lc4 + 1][lrow] = bv.y;
    Bs[lc4 + 2][lrow] = bv.z; Bs[lc4 + 3][lrow] = bv.w;
    __syncthreads();
#pragma unroll
    for (int k = 0; k < BK; ++k) {
      float4 a = *(const float4*)&As[k][ty << 2];
      float4 b = *(const float4*)&Bs[k][tx << 2];
      acc[0][0] += a.x * b.x; acc[0][1] += a.x * b.y; acc[0][2] += a.x * b.z; acc[0][3] += a.x * b.w;
      acc[1][0] += a.y * b.x; acc[1][1] += a.y * b.y; acc[1][2] += a.y * b.z; acc[1][3] += a.y * b.w;
      acc[2][0] += a.z * b.x; acc[2][1] += a.z * b.y; acc[2][2] += a.z * b.z; acc[2][3] += a.z * b.w;
      acc[3][0] += a.w * b.x; acc[3][1] += a.w * b.y; acc[3][2] += a.w * b.z; acc[3][3] += a.w * b.w;
    }
    __syncthreads();
  }
#pragma unroll
  for (int i = 0; i < 4; ++i) {
    int m = m0 + (ty << 2) + i;
#pragma unroll
    for (int j = 0; j < 4; ++j) {
      int n = n0 + (tx << 2) + j;
      if (n < NG) pre[(size_t)m * NG + n] = acc[i][j] + bih[n] + bhh[n];
    }
  }
}

// ---------------------------------------------------------------- sync init
// hbuf: 2*HSLOT u64 slots, each = (float_bits << 32) | step_tag.
// tag 0 + h=0.0 in buffer 0 is the valid h_0; buffer 1 tags (wanted: odd) never match 0.
__global__ void init_sync(u64* hbuf) {
  int i = threadIdx.x;
  if (i < 2 * HSLOT) hbuf[i] = 0ull;
}

// ---------------------------------------------------------------- recurrence
__device__ __forceinline__ uint f2bf(float f) {
  uint u = __float_as_uint(f);
  return (u + 0x7fffu + ((u >> 16) & 1u)) >> 16;  // RNE to bf16
}
__device__ __forceinline__ float sigm(float x) { return 1.f / (1.f + __expf(-x)); }
__device__ __forceinline__ float fast_tanh(float x) {
  x = fminf(fmaxf(x, -15.f), 15.f);
  float e = __expf(2.f * x);
  return (e - 1.f) / (e + 1.f);
}

__global__ __launch_bounds__(TPB) void lstm_seq(const float* __restrict__ pre,
                                                const float* __restrict__ Whh,
                                                const float* __restrict__ fcw,
                                                const float* __restrict__ fcb,
                                                u64* hbuf,
                                                float* __restrict__ out) {
  __shared__ uint Wl[RWS][256];      // bf16-pair packed, cols padded to 512
  __shared__ float h_lds[HSLOT];
  __shared__ float gates[RWS];
  __shared__ float c_lds[UPW];

  const int g = blockIdx.x;
  const int tid = threadIdx.x;
  const int r = tid >> 3;            // local gate-row 0..39
  const int cc = tid & 7;            // col-chunk lane 0..7
  const int my_prerow = (r / UPW) * HID + g * UPW + (r % UPW);

  // stage W_hh slice: local row r = gate*UPW + ul -> global row gate*HID + g*UPW + ul
  for (int i = tid; i < RWS * 256; i += TPB) {
    int rr = i >> 8, cp = i & 255;
    int gi = rr / UPW, ul = rr % UPW;
    size_t grow = (size_t)(gi * HID + g * UPW + ul) * HID;
    int c0 = cp * 2, c1 = c0 + 1;
    float v0 = (c0 < HID) ? Whh[grow + c0] : 0.f;
    float v1 = (c1 < HID) ? Whh[grow + c1] : 0.f;
    Wl[rr][cp] = f2bf(v0) | (f2bf(v1) << 16);
  }
  if (tid < UPW) c_lds[tid] = 0.f;
  if (tid < HSLOT - HID) h_lds[HID + tid] = 0.f;  // pads, written once

  // interleaved chunks: lane (r,cc), chunk q covers packed cols q*32+cc*4..+3
  // (real cols 64q+8cc..+7). W bank = (cc*4+j)%32 -> all 32 banks across cc.
  const uint* wrow = &Wl[r][cc * 4];
  const int need0 = (tid < HID);
  const int need1 = (tid + TPB < HID);

  for (int t = 0; t < SEQ; ++t) {
    // issue pre load before the poll so its latency overlaps the handshake
    float pre_v = 0.f;
    if (cc == 0) pre_v = pre[(size_t)t * NG + my_prerow];

    // poll h_t directly from the tagged double buffer (no flags, no fences)
    const u64* hb = hbuf + (t & 1) * HSLOT;
    const uint want = (uint)t;
    float hv0 = 0.f, hv1 = 0.f;
    int ok0 = !need0, ok1 = !need1;
    for (;;) {
      if (!ok0) {
        u64 u = __hip_atomic_load(&hb[tid], __ATOMIC_RELAXED, __HIP_MEMORY_SCOPE_AGENT);
        if ((uint)u == want) { hv0 = __uint_as_float((uint)(u >> 32)); ok0 = 1; }
      }
      if (!ok1) {
        u64 u = __hip_atomic_load(&hb[tid + TPB], __ATOMIC_RELAXED, __HIP_MEMORY_SCOPE_AGENT);
        if ((uint)u == want) { hv1 = __uint_as_float((uint)(u >> 32)); ok1 = 1; }
      }
      if (__syncthreads_and(ok0 && ok1)) break;
    }
    if (need0) h_lds[tid] = hv0;
    if (need1) h_lds[tid + TPB] = hv1;
    __syncthreads();

    // matvec: 8 chunks of 8 real cols per lane, bank-conflict-minimal
    float acc = 0.f;
#pragma unroll
    for (int q = 0; q < 8; ++q) {
      uint4 u = *(const uint4*)(wrow + q * 32);
      float4 h0 = *(const float4*)&h_lds[q * 64 + cc * 8];
      float4 h1 = *(const float4*)&h_lds[q * 64 + cc * 8 + 4];
      acc += __uint_as_float(u.x << 16) * h0.x;
      acc += __uint_as_float(u.x & 0xffff0000u) * h0.y;
      acc += __uint_as_float(u.y << 16) * h0.z;
      acc += __uint_as_float(u.y & 0xffff0000u) * h0.w;
      acc += __uint_as_float(u.z << 16) * h1.x;
      acc += __uint_as_float(u.z & 0xffff0000u) * h1.y;
      acc += __uint_as_float(u.w << 16) * h1.z;
      acc += __uint_as_float(u.w & 0xffff0000u) * h1.w;
    }
    acc += __shfl_xor(acc, 1);
    acc += __shfl_xor(acc, 2);
    acc += __shfl_xor(acc, 4);
    if (cc == 0) gates[r] = acc + pre_v;
    __syncthreads();

    if (tid < UPW) {
      float iv = sigm(gates[tid]);
      float fv = sigm(gates[UPW + tid]);
      float gv = fast_tanh(gates[2 * UPW + tid]);
      float ov = sigm(gates[3 * UPW + tid]);
      float c = fv * c_lds[tid] + iv * gv;
      c_lds[tid] = c;
      float h = ov * fast_tanh(c);
      u64 pk = ((u64)__float_as_uint(h) << 32) | (u64)(uint)(t + 1);
      __hip_atomic_store(&hbuf[((t + 1) & 1) * HSLOT + g * UPW + tid], pk,
                         __ATOMIC_RELAXED, __HIP_MEMORY_SCOPE_AGENT);
    }
    // no trailing barrier: next iteration's __syncthreads_and orders LDS reuse
  }

  // final FC by WG 0: out = fc_w @ h_SEQ + fc_b   (h_SEQ lives in buffer SEQ&1 = 0)
  if (g == 0) {
    const u64* hb = hbuf + (SEQ & 1) * HSLOT;
    const uint want = (uint)SEQ;
    float hv0 = 0.f, hv1 = 0.f;
    int ok0 = !need0, ok1 = !need1;
    for (;;) {
      if (!ok0) {
        u64 u = __hip_atomic_load(&hb[tid], __ATOMIC_RELAXED, __HIP_MEMORY_SCOPE_AGENT);
        if ((uint)u == want) { hv0 = __uint_as_float((uint)(u >> 32)); ok0 = 1; }
      }
      if (!ok1) {
        u64 u = __hip_atomic_load(&hb[tid + TPB], __ATOMIC_RELAXED, __HIP_MEMORY_SCOPE_AGENT);
        if ((uint)u == want) { hv1 = __uint_as_float((uint)(u >> 32)); ok1 = 1; }
      }
      if (__syncthreads_and(ok0 && ok1)) break;
    }
    if (need0) h_lds[tid] = hv0;
    if (need1) h_lds[tid + TPB] = hv1;
    __syncthreads();
    int row = tid >> 4, ln = tid & 15;   // 20 rows x 16 lanes = 320
    float s = 0.f;
    for (int j = ln; j < HID; j += 16) s += fcw[row * HID + j] * h_lds[j];
    s += __shfl_xor(s, 1); s += __shfl_xor(s, 2);
    s += __shfl_xor(s, 4); s += __shfl_xor(s, 8);
    if (ln == 0) out[row] = s + fcb[row];
  }
}

// ---------------------------------------------------------------- launch
extern "C" void kernel_launch(void* const* d_in, const int* in_sizes, int n_in,
                              void* d_out, int out_size, void* d_ws, size_t ws_size,
                              hipStream_t stream) {
  const int* words = (const int*)d_in[0];
  const int* labels = (const int*)d_in[1];
  const float* embw = (const float*)d_in[2];
  const float* embe = (const float*)d_in[3];
  const float* Wih = (const float*)d_in[4];
  const float* Whh = (const float*)d_in[5];
  const float* bih = (const float*)d_in[6];
  const float* bhh = (const float*)d_in[7];
  const float* fcw = (const float*)d_in[8];
  const float* fcb = (const float*)d_in[9];
  float* out = (float*)d_out;

  char* ws = (char*)d_ws;
  float* x = (float*)ws;                                             // 4096*608*4  = 9.96 MB
  float* pre = (float*)(ws + (size_t)SEQ * KXP * 4);                 // 4096*2000*4 = 32.77 MB
  u64* hbuf = (u64*)(ws + (size_t)SEQ * KXP * 4 + (size_t)SEQ * NG * 4);  // 2*512*8 = 8 KB

  gather_x<<<SEQ, 256, 0, stream>>>(words, labels, embw, embe, x);
  dim3 ggrid(SEQ / BM, (NG + BN - 1) / BN);
  gemm_pre<<<ggrid, 256, 0, stream>>>(x, Wih, bih, bhh, pre);
  init_sync<<<1, 1024, 0, stream>>>(hbuf);
  lstm_seq<<<NWG, TPB, 0, stream>>>(pre, Whh, fcw, fcb, hbuf, out);
}